// Round 15
// baseline (870.200 us; speedup 1.0000x reference)
//
#include <hip/hip_runtime.h>
#include <hip/hip_bf16.h>
#include <hip/hip_fp16.h>
#include <stdint.h>

// Problem constants (match reference)
#define NN   10000
#define GG   100
#define NPG  100
#define EE   400000
#define EPG  4000
#define CC   32
#define LM   16
#define SS   4
#define NBES 8
#define NLAYER 3
#define INV_AVG (1.0f/40.0f)
#define MLPB 6256   // mlp block count (8*782 >= EE/64), 256-thread units
#define MLPB2 3128  // paired mlp blocks (2 units per 512-thread k_gather block)

typedef _Float16 f16x8 __attribute__((ext_vector_type(8)));
typedef _Float16 f16x4 __attribute__((ext_vector_type(4)));
typedef _Float16 f16x2 __attribute__((ext_vector_type(2)));
typedef float    f32x4 __attribute__((ext_vector_type(4)));

__device__ __forceinline__ float siluf(float x) { return x / (1.0f + __expf(-x)); }
__device__ __forceinline__ int lof(int m) { return (m >= 1) + (m >= 4) + (m >= 9); }
__device__ __forceinline__ f16x2 asf16x2(unsigned u) {
  union { unsigned u; f16x2 f; } x; x.u = u; return x.f;
}

// async global->LDS, 16B per lane; LDS dst = uniform base + lane*16
__device__ __forceinline__ void gload_lds16(const void* g, void* l) {
  __builtin_amdgcn_global_load_lds(
      (const __attribute__((address_space(1))) unsigned int*)g,
      (__attribute__((address_space(3))) unsigned int*)l, 16, 0, 0);
}

// ---------------------------------------------------------------------------
// geometry body (per edge): Y[E,16] f16, ef[E,8] f16
// ---------------------------------------------------------------------------
__device__ __forceinline__ void geom_body(
    int e, const float* __restrict__ pos, const float* __restrict__ cell,
    const int* __restrict__ Sij, const int* __restrict__ eidx,
    const int* __restrict__ batch, __half* __restrict__ Y, __half* __restrict__ ef)
{
  int ia = eidx[e], ja = eidx[EE + e];
  int g = batch[ia];
  float s0 = (float)Sij[e*3+0], s1 = (float)Sij[e*3+1], s2 = (float)Sij[e*3+2];
  const float* cg = cell + g*9;
  float shx = s0*cg[0] + s1*cg[3] + s2*cg[6];
  float shy = s0*cg[1] + s1*cg[4] + s2*cg[7];
  float shz = s0*cg[2] + s1*cg[5] + s2*cg[8];
  float rx = (pos[ja*3+0] - pos[ia*3+0] + shx) / 6.0f;
  float ry = (pos[ja*3+1] - pos[ia*3+1] + shy) / 6.0f;
  float rz = (pos[ja*3+2] - pos[ia*3+2] + shz) / 6.0f;
  float r2 = rx*rx + ry*ry + rz*rz;
  float r  = sqrtf(r2);
  float rs = (r > 1e-9f) ? r : 1e-9f;
  float inv = 1.0f / rs;
  float x = rx*inv, y = ry*inv, z = rz*inv;

  const float s3   = 1.7320508075688772f;
  const float s15  = 3.872983346207417f;
  const float s5h  = 1.118033988749895f;
  const float s15h = 1.9364916731037085f;
  const float s358 = 2.091650066335189f;
  const float s105 = 10.246950765959598f;
  const float s218 = 1.620185174601965f;
  const float s7h  = 1.3228756555322954f;
  const float s105h= 5.123475382979799f;

  float xx = x*x, yy = y*y, zz = z*z;
  float yv[16];
  yv[0]  = 1.0f;
  yv[1]  = s3*x;  yv[2] = s3*y;  yv[3] = s3*z;
  yv[4]  = s15*x*y; yv[5] = s15*y*z; yv[6] = s5h*(3.0f*zz - 1.0f);
  yv[7]  = s15*x*z; yv[8] = s15h*(xx - yy);
  yv[9]  = s358*y*(3.0f*xx - yy);
  yv[10] = s105*x*y*z;
  yv[11] = s218*y*(5.0f*zz - 1.0f);
  yv[12] = s7h*(5.0f*zz*z - 3.0f*z);
  yv[13] = s218*x*(5.0f*zz - 1.0f);
  yv[14] = s105h*z*(xx - yy);
  yv[15] = s358*x*(xx - 3.0f*yy);

  union { __half h[16]; uint4 u[2]; } yp;
  #pragma unroll
  for (int i = 0; i < 16; ++i) yp.h[i] = __float2half(yv[i]);
  uint4* Yp = (uint4*)(Y + (size_t)e*16);
  Yp[0] = yp.u[0];
  Yp[1] = yp.u[1];

  float f = 0.0f;
  if (r < 1.0f) f = 1.0f - 6.0f*r2 + 8.0f*r2*r - 3.0f*r2*r2;
  float c1 = 1.4142135623730951f * f * inv;
  float ang = 3.14159265358979323846f * rs;
  float sn = __sinf(ang), cn = __cosf(ang);
  float twoc = 2.0f * cn;
  float sprev = 0.0f, scur = sn;
  union { __half h[8]; uint4 u; } p;
  #pragma unroll
  for (int n1 = 1; n1 <= NBES; ++n1) {
    p.h[n1-1] = __float2half(c1 * scur);
    float snext = twoc * scur - sprev;
    sprev = scur; scur = snext;
  }
  *(uint4*)(ef + (size_t)e*8) = p.u;
}

// ---------------------------------------------------------------------------
// k_pre: geom (1563) | init (1250) | wconv+hu0 (192) | csr_count (1563)
// ---------------------------------------------------------------------------
__global__ __launch_bounds__(256) void k_pre(
    const float* __restrict__ pos, const float* __restrict__ cell,
    const int* __restrict__ Sij, const int* __restrict__ eidx,
    const int* __restrict__ batch, __half* __restrict__ Y, __half* __restrict__ ef,
    const int* __restrict__ species, const float* __restrict__ W_emb,
    const float* __restrict__ W_xtp, float* __restrict__ h,
    float* __restrict__ xnode, float* __restrict__ node_e,
    const float* __restrict__ W2, const float* __restrict__ W3,
    _Float16* __restrict__ W2t, _Float16* __restrict__ W3t,
    const float* __restrict__ W_up0, float* __restrict__ hu0,
    int* __restrict__ cnt)
{
  int b = blockIdx.x, t = threadIdx.x;
  if (b < 1563) {
    int e = b*256 + t;
    if (e < EE) geom_body(e, pos, cell, Sij, eidx, batch, Y, ef);
  } else if (b < 2813) {
    int idx = (b - 1563)*256 + t;
    if (idx < NN*CC) {
      int n = idx / CC, c = idx % CC;
      int sp = species[n];
      float h0 = W_emb[sp*CC + c];
      float* hp = h + (size_t)n*512 + c*16;
      hp[0] = h0;
      #pragma unroll
      for (int m = 1; m < 16; ++m) hp[m] = 0.0f;
      if (c == 0) {
        float xn = 0.0f;
        for (int c2 = 0; c2 < CC; ++c2) xn += W_emb[sp*CC + c2] * W_xtp[c2*SS + sp];
        xnode[n] = xn;
        node_e[n] = 0.0f;
      }
    }
  } else if (b < 3005) {
    int idx = (b - 2813)*256 + t;
    if (idx < NLAYER*64*64) {
      int l = idx / 4096, rem = idx % 4096, k = rem / 64, j = rem % 64;
      W2t[l*4096 + j*64 + k] = (_Float16)W2[idx];
    }
    if (idx < NLAYER*64*256) {
      int l = idx / 16384, rem = idx % 16384, k = rem / 256, j = rem % 256;
      W3t[l*16384 + j*64 + k] = (_Float16)W3[idx];
    }
    // layer-0 hu table: hu0[sp][d] = sum_c W_emb[sp,c] * W_up[0,0,c,d]
    if (b == 2813 && idx < SS*CC) {
      int sp = idx >> 5, dd = idx & 31;
      float p0 = 0.0f, p1 = 0.0f;
      for (int c2 = 0; c2 < 16; ++c2)  p0 += W_emb[sp*CC + c2] * W_up0[c2*32 + dd];
      for (int c2 = 16; c2 < 32; ++c2) p1 += W_emb[sp*CC + c2] * W_up0[c2*32 + dd];
      hu0[idx] = p0 + p1;
    }
  } else {
    int e = (b - 3005)*256 + t;
    if (e < EE) atomicAdd(&cnt[eidx[e]], 1);
  }
}

// ---------------------------------------------------------------------------
// CSR scan
// ---------------------------------------------------------------------------
__global__ __launch_bounds__(128) void k_csr_scan(
    const int* __restrict__ cnt, int* __restrict__ off, int* __restrict__ cursor) {
  __shared__ int s[128];
  int g = blockIdx.x, t = threadIdx.x;
  int own = (t < NPG) ? cnt[g*NPG + t] : 0;
  s[t] = own;
  __syncthreads();
  #pragma unroll
  for (int d = 1; d < 128; d <<= 1) {
    int v = (t >= d) ? s[t-d] : 0;
    __syncthreads();
    s[t] += v;
    __syncthreads();
  }
  if (t < NPG) {
    int o = g*EPG + s[t] - own;
    off[g*NPG + t] = o;
    cursor[g*NPG + t] = o;
    if (g == GG-1 && t == NPG-1) off[NN] = EE;
  }
}

// ---------------------------------------------------------------------------
// mlp body (per 256-thread unit, 64 edges): ef(8)->hm1(64) VALU -> hm2(64) MFMA
// ---------------------------------------------------------------------------
__device__ __forceinline__ void mlp_body(
    int mb, int t, _Float16* pool16,
    const __half* __restrict__ ef, const float* __restrict__ W1,
    const float* __restrict__ b1, const _Float16* __restrict__ W2t,
    const float* __restrict__ b2, __half* __restrict__ hm2)
{
  int eb = (mb & 7) * 782 + (mb >> 3);
  if (eb >= EE/64) return;
  int wv = t >> 6, lane = t & 63;
  int ln15 = lane & 15, quad = lane >> 4;
  _Float16* hm1 = pool16 + wv*(16*72);
  size_t e16 = (size_t)eb*64 + wv*16;

  union { uint4 u; __half hh[8]; } efv;
  efv.u = *(const uint4*)(ef + (e16 + ln15)*8);
  float ev[8];
  #pragma unroll
  for (int k = 0; k < 8; ++k) ev[k] = __half2float(efv.hh[k]);
  #pragma unroll
  for (int p = 0; p < 4; ++p) {
    int j0 = p*16 + quad*4;
    float4 a = *(const float4*)(b1 + j0);
    #pragma unroll
    for (int k = 0; k < 8; ++k) {
      const float4 w = *(const float4*)(W1 + k*64 + j0);
      a.x += ev[k]*w.x; a.y += ev[k]*w.y; a.z += ev[k]*w.z; a.w += ev[k]*w.w;
    }
    f16x4 pk;
    pk[0] = (_Float16)siluf(a.x);
    pk[1] = (_Float16)siluf(a.y);
    pk[2] = (_Float16)siluf(a.z);
    pk[3] = (_Float16)siluf(a.w);
    *(f16x4*)&hm1[ln15*72 + j0] = pk;
  }

  f16x8 a0 = *(const f16x8*)(hm1 + ln15*72 + quad*8);
  f16x8 a1 = *(const f16x8*)(hm1 + ln15*72 + 32 + quad*8);
  #pragma unroll
  for (int cg = 0; cg < 4; ++cg) {
    int col = cg*16 + ln15;
    f32x4 d = {0.f, 0.f, 0.f, 0.f};
    d = __builtin_amdgcn_mfma_f32_16x16x32_f16(a0, *(const f16x8*)(W2t + (size_t)col*64 + quad*8), d, 0, 0, 0);
    d = __builtin_amdgcn_mfma_f32_16x16x32_f16(a1, *(const f16x8*)(W2t + (size_t)col*64 + 32 + quad*8), d, 0, 0, 0);
    float bb = b2[col];
    #pragma unroll
    for (int r = 0; r < 4; ++r)
      hm2[(e16 + quad*4 + r)*64 + col] = __float2half(siluf(d[r] + bb));
  }
}

// standalone mlp (used by the non-fused fallback path)
__global__ __launch_bounds__(256) void k_mlp(
    const __half* __restrict__ ef, const float* __restrict__ W1,
    const float* __restrict__ b1, const _Float16* __restrict__ W2t,
    const float* __restrict__ b2, __half* __restrict__ hm2)
{
  __shared__ _Float16 pool16[4*16*72];
  mlp_body(blockIdx.x, threadIdx.x, pool16, ef, W1, b1, W2t, b2, hm2);
}

// ---------------------------------------------------------------------------
// k_csr_fill: edges fill (1563) | layer-0 hu fill (1250) | layer-0 mlp (MLPB)
// ---------------------------------------------------------------------------
__global__ __launch_bounds__(256) void k_csr_fill(
    const int* __restrict__ eidx, int* __restrict__ cursor, int2* __restrict__ elist,
    const float* __restrict__ hu0, const int* __restrict__ species,
    __half* __restrict__ huA,
    const __half* __restrict__ ef, const float* __restrict__ W1,
    const float* __restrict__ b1, const _Float16* __restrict__ W2t,
    const float* __restrict__ b2, __half* __restrict__ hm2) {
  __shared__ _Float16 pool16[4*16*72];
  int b = blockIdx.x;
  if (b < 1563) {
    int e = b * 256 + threadIdx.x;
    if (e >= EE) return;
    int ia = eidx[e], ja = eidx[EE + e];
    int pos = atomicAdd(&cursor[ia], 1);
    elist[pos] = make_int2(e*128, ja*1024);
    return;
  }
  if (b < 2813) {
    int idx = (b - 1563)*256 + threadIdx.x;   // [0, NN*32)
    if (idx >= NN*CC) return;
    int n = idx >> 5, d = idx & 31;
    __half h0 = __float2half(hu0[species[n]*CC + d]);
    union { __half hh[2]; unsigned u; } w; w.hh[0] = h0; w.hh[1] = __half(0.0f);
    uint4 v0 = make_uint4(w.u, 0u, 0u, 0u);
    uint4 v1 = make_uint4(0u, 0u, 0u, 0u);
    uint4* p = (uint4*)(huA + (size_t)n*512 + d*16);
    p[0] = v0;
    p[1] = v1;
    return;
  }
  mlp_body(b - 2813, threadIdx.x, pool16, ef, W1, b1, W2t, b2, hm2);
}

// ---------------------------------------------------------------------------
// k_gather: 512-thread blocks = TWO independent 256-thread node-units.
//
// R28 residency experiment, correctly this time. R5's NaN root cause:
// the tile loop ran a deg-dependent number of __syncthreads per unit ->
// barrier divergence across units. Fix: both units loop over
// ntmax = max(ntiles0, ntiles1) (exchanged via shared ints + 1 barrier);
// inactive iterations skip work but hit every barrier -> block-uniform
// barrier count by construction.
// Per-unit pipeline = R14 verbatim (TILE=16, LDS-staged hu/Y, post-barrier
// prefetch, verified 262us/dispatch) on its own 26624B LDS partition.
// Theory under test: the ~3.5 resident BLOCKS/CU cap seen all session is
// per-block -> 512-thread blocks double resident waves (3 LDS-capped
// blocks x 8 waves = 24 waves/CU vs today's 14).
// Discriminator: OccupancyPercent (65-75% = confirmed; ~44% = refuted).
// ---------------------------------------------------------------------------
__global__ __launch_bounds__(512) void k_gather(
    const int2* __restrict__ elist, const int* __restrict__ off,
    const __half* __restrict__ Y, const __half* __restrict__ hm2,
    const _Float16* __restrict__ W3t, const __half* __restrict__ hu_in,
    const int* __restrict__ species, const float* __restrict__ xnode,
    const float* __restrict__ Wd, const float* __restrict__ Wsc,
    const float* __restrict__ Wr1, const float* __restrict__ br1,
    const float* __restrict__ Wr2, float* __restrict__ node_e,
    const float* __restrict__ Wu_next, __half* __restrict__ hu_out,
    float* __restrict__ h, int has_next,
    int do_mlp, const __half* __restrict__ ef,
    const float* __restrict__ W1n, const float* __restrict__ b1n,
    const _Float16* __restrict__ W2tn, const float* __restrict__ b2n,
    __half* __restrict__ hm2_next)
{
  __shared__ float pool[13312];   // 2 units x 6656 floats = 53248 B
  __shared__ int nt2[2];

  int b = blockIdx.x, t = threadIdx.x;
  int unit = t >> 8, tt = t & 255;
  if (do_mlp) {
    if (b < MLPB2) {
      // unit mlp pools: halfword offsets 0 / 4608 (9216 B each)
      mlp_body(b*2 + unit, tt, (_Float16*)pool + unit*4608,
               ef, W1n, b1n, W2tn, b2n, hm2_next);
      return;
    }
    b -= MLPB2;
  }
  float* upool = pool + unit*6656;
  _Float16* rw_base = (_Float16*)upool;
  char* hu_sc = (char*)upool + 8704;
  char* Ys_c  = (char*)upool + 25600;
  float* al_s = upool;
  float* h2_s = upool + 512;

  int u = b*2 + unit;
  int n = (u & 7) * (NN/8) + (u >> 3);   // XCD-locality swizzle
  int beg = off[n], deg = off[n+1] - beg;

  int lane = tt & 63, wv = tt >> 6;
  int ln15 = lane & 15, quad = lane >> 4;
  _Float16* rww = rw_base + wv*(16*68);
  const char* rwc = (const char*)rww;
  const char* hm2c = (const char*)hm2;
  const char* Yc   = (const char*)Y;
  const char* huc  = (const char*)hu_in;

  float hreg0 = h[(size_t)n*512 + tt];
  float hreg1 = h[(size_t)n*512 + tt + 256];

  // edge-loop lane mapping: lane = half*32 + cl*4 + mq
  int mq   = lane & 3;          // m-quad: m = mq*4 .. mq*4+3
  int cl   = (lane >> 2) & 7;   // channel within wave
  int half = lane >> 5;         // edge parity
  int c    = wv*8 + cl;
  int m0q  = mq*4;
  int la0 = lof(m0q),   lb0 = lof(m0q+1);
  int la1 = lof(m0q+2), lb1 = lof(m0q+3);
  unsigned sel0 = (unsigned)(2*la0) | ((unsigned)(2*la0+1)<<8)
                | ((unsigned)(2*lb0)<<16) | ((unsigned)(2*lb0+1)<<24);
  unsigned sel1 = (unsigned)(2*la1) | ((unsigned)(2*la1+1)<<8)
                | ((unsigned)(2*lb1)<<16) | ((unsigned)(2*lb1+1)<<24);
  unsigned huconst = (unsigned)(c*32 + mq*8);

  // persistent W3 fragments: this wave's 64 output columns
  f16x8 w3A[4], w3B[4];
  #pragma unroll
  for (int cg = 0; cg < 4; ++cg) {
    int colg = (cg < 2) ? (wv*32 + cg*16 + ln15)
                        : (128 + wv*32 + (cg-2)*16 + ln15);
    w3A[cg] = *(const f16x8*)(W3t + (size_t)colg*64 + quad*8);
    w3B[cg] = *(const f16x8*)(W3t + (size_t)colg*64 + 32 + quad*8);
  }

  // exchange tile counts (uniform barrier #0)
  if (tt == 0) nt2[unit] = (deg + 15) >> 4;
  __syncthreads();
  int ntmax = max(nt2[0], nt2[1]);

  float acc0 = 0.f, acc1 = 0.f, acc2 = 0.f, acc3 = 0.f;

  int2 el_cur = make_int2(0, 0);
  f16x8 aA0 = {}, aA1 = {};
  if (deg > 0) {
    int idx = lane < deg ? lane : deg - 1;
    el_cur = elist[beg + idx];
    int eA = __shfl(el_cur.x, ln15);
    aA0 = *(const f16x8*)(hm2c + (unsigned)eA + quad*16);
    aA1 = *(const f16x8*)(hm2c + (unsigned)eA + 64 + quad*16);
  }

  // compute body for edge slot s (all operands in LDS)
  auto edge_compute = [&](int s, f16x2& av0, f16x2& av1) {
    uint2 hj = *(const uint2*)(hu_sc + (unsigned)s*1056 + huconst);   // ds_read_b64
    unsigned hj0b = (unsigned)__builtin_amdgcn_mov_dpp((int)hj.x, 0, 0xf, 0xf, true);
    unsigned hj0s = __builtin_amdgcn_perm(hj0b, hj0b, 0x01000100u);   // splat m=0
    uint2 Ymv = *(const uint2*)(Ys_c + (unsigned)s*32 + mq*8);        // ds_read_b64
    uint2 w0q = *(const uint2*)(rwc + (unsigned)s*136 + cl*8);        // ds_read_b64
    uint2 w1q = *(const uint2*)(rwc + (unsigned)s*136 + cl*8 + 64);   // ds_read_b64
    unsigned w00 = __builtin_amdgcn_perm(w0q.y, w0q.x, sel0);
    unsigned w01 = __builtin_amdgcn_perm(w0q.y, w0q.x, sel1);
    unsigned w10 = __builtin_amdgcn_perm(w1q.y, w1q.x, sel0);
    unsigned w11 = __builtin_amdgcn_perm(w1q.y, w1q.x, sel1);
    f16x2 hj0v = asf16x2(hj0s);
    av0 += asf16x2(w00) * (asf16x2(Ymv.x) * hj0v) + asf16x2(w10) * asf16x2(hj.x);
    av1 += asf16x2(w01) * (asf16x2(Ymv.y) * hj0v) + asf16x2(w11) * asf16x2(hj.y);
  };

  for (int tc = 0; tc < ntmax; ++tc) {
    int base = tc*16;
    bool active = base < deg;
    int cnt = 0;
    if (active) { cnt = deg - base; if (cnt > 16) cnt = 16; }

    if (tc > 0) __syncthreads();   // A (uniform): prior compute done

    if (active) {
      // STAGE: hu rows (4 per wave, 1KB each, async) + Y rows (wave 0)
      #pragma unroll
      for (int q = 0; q < 4; ++q) {
        int s = wv*4 + q;
        if (s < cnt) {
          int rowoff = __shfl(el_cur.y, s);
          gload_lds16(huc + (unsigned)rowoff + lane*16, hu_sc + s*1056);
        }
      }
      if (wv == 0) {
        int yoff = __shfl(el_cur.x, lane >> 1) >> 2;   // e*32 byte offset
        gload_lds16(Yc + (unsigned)yoff + (lane & 1)*16, Ys_c);
      }

      // MFMA phase (reg-resident W3; no VMEM) + packed ds_write
      __builtin_amdgcn_s_setprio(1);
      #pragma unroll
      for (int cg = 0; cg < 4; ++cg) {
        f32x4 dA = {0.f, 0.f, 0.f, 0.f};
        dA = __builtin_amdgcn_mfma_f32_16x16x32_f16(w3A[cg], aA0, dA, 0, 0, 0);
        dA = __builtin_amdgcn_mfma_f32_16x16x32_f16(w3B[cg], aA1, dA, 0, 0, 0);
        f16x4 pA;
        #pragma unroll
        for (int r = 0; r < 4; ++r) pA[r] = (_Float16)dA[r];
        *(f16x4*)&rww[ln15*68 + cg*16 + quad*4] = pA;      // ds_write_b64
      }
      __builtin_amdgcn_s_setprio(0);
    }

    __syncthreads();   // B (uniform): staged hu/Y + rww visible

    if (active) {
      // PREFETCH k+1 (lands under the compute phase)
      int2 el_nxt = el_cur;
      f16x8 nA0 = aA0, nA1 = aA1;
      if (base + 16 < deg) {
        int idx = base + 16 + lane;
        if (idx >= deg) idx = deg - 1;
        el_nxt = elist[beg + idx];
        int eA = __shfl(el_nxt.x, ln15);
        nA0 = *(const f16x8*)(hm2c + (unsigned)eA + quad*16);
        nA1 = *(const f16x8*)(hm2c + (unsigned)eA + 64 + quad*16);
      }

      // COMPUTE: pure VALU + LDS, halves split the edges
      f16x2 av0 = {(_Float16)0.f, (_Float16)0.f};
      f16x2 av1 = {(_Float16)0.f, (_Float16)0.f};
      int nfull = cnt >> 1;
      #pragma unroll 8
      for (int i = 0; i < nfull; ++i) edge_compute(2*i + half, av0, av1);
      if ((cnt & 1) && half == 0) edge_compute(cnt - 1, av0, av1);
      acc0 += (float)av0[0]; acc1 += (float)av0[1];
      acc2 += (float)av1[0]; acc3 += (float)av1[1];

      el_cur = el_nxt;
      aA0 = nA0; aA1 = nA1;
    }
  }

  // combine the two edge-halves
  acc0 += __shfl_xor(acc0, 32);
  acc1 += __shfl_xor(acc1, 32);
  acc2 += __shfl_xor(acc2, 32);
  acc3 += __shfl_xor(acc3, 32);

  __syncthreads();   // tile phase done (both units) -> overlay safe

  if (half == 0) {
    *(float4*)&al_s[c*16 + m0q] =
        make_float4(acc0*INV_AVG, acc1*INV_AVG, acc2*INV_AVG, acc3*INV_AVG);
  }
  h2_s[tt]       = hreg0;
  h2_s[tt + 256] = hreg1;
  __syncthreads();

  int sp = species[n];
  float xn = xnode[n];
  int d = lane & 31, ch = lane >> 5;
  #pragma unroll
  for (int mi = 0; mi < 4; ++mi) {
    int m = wv*4 + mi;
    int l = lof(m);
    const float* wd  = Wd  + l*1024 + d;
    const float* wsc = Wsc + l*4096 + sp*32 + d;
    float a = 0.0f, s = 0.0f;
    #pragma unroll 4
    for (int cc = 0; cc < 16; ++cc) {
      int c2 = cc + ch*16;
      a += al_s[c2*16 + m] * wd[c2*32];
      s += h2_s[c2*16 + m] * wsc[c2*128];
    }
    a += __shfl_xor(a, 32);
    s += __shfl_xor(s, 32);
    float hn = a*xn + s;
    if (ch == 0) h2_s[d*16 + m] = hn;       // out overlay (wave-excl col)
    if (has_next) {
      const float* wu = Wu_next + l*1024 + d;
      float uacc = 0.0f;
      #pragma unroll 4
      for (int cc = 0; cc < 16; ++cc) {
        int c2 = cc + ch*16;
        uacc += h2_s[c2*16 + m] * wu[c2*32];    // reads out (same wave wrote)
      }
      uacc += __shfl_xor(uacc, 32);
      if (ch == 0) al_s[d*16 + m] = uacc;     // hu overlay (wave-excl col)
    }
  }

  if (tt < 64) {
    float pre = br1[tt];
    #pragma unroll 4
    for (int cc = 0; cc < CC; ++cc) pre += h2_s[cc*16] * Wr1[cc*64 + tt];
    float v = siluf(pre) * Wr2[tt];
    #pragma unroll
    for (int off2 = 32; off2 > 0; off2 >>= 1) v += __shfl_down(v, off2);
    if (tt == 0) node_e[n] += siluf(v);
  }
  __syncthreads();   // out/hu complete (both units)

  h[(size_t)n*512 + tt]       = h2_s[tt];
  h[(size_t)n*512 + tt + 256] = h2_s[tt + 256];
  if (has_next) {
    __half2 o;
    o.x = __float2half(al_s[2*tt]);
    o.y = __float2half(al_s[2*tt + 1]);
    *(__half2*)(hu_out + (size_t)n*512 + 2*tt) = o;
  }
}

// ---------------------------------------------------------------------------
// Kernel: per-graph sum of node energies
// ---------------------------------------------------------------------------
__global__ __launch_bounds__(128) void k_out(
    const float* __restrict__ node_e, float* __restrict__ out)
{
  int g = blockIdx.x, t = threadIdx.x;
  float v = (t < NPG) ? node_e[g*NPG + t] : 0.0f;
  #pragma unroll
  for (int off2 = 32; off2 > 0; off2 >>= 1) v += __shfl_down(v, off2);
  __shared__ float r2[2];
  if ((t & 63) == 0) r2[t >> 6] = v;
  __syncthreads();
  if (t == 0) out[g] = r2[0] + r2[1];
}

// Diagnostic: if workspace too small, report its size (MB) via absmax
__global__ void k_dbg(float* __restrict__ out, float v) {
  int i = blockIdx.x * 64 + threadIdx.x;
  if (i < GG) out[i] = v;
}

// ---------------------------------------------------------------------------
extern "C" void kernel_launch(void* const* d_in, const int* in_sizes, int n_in,
                              void* d_out, int out_size, void* d_ws, size_t ws_size,
                              hipStream_t stream)
{
  const float* positions = (const float*)d_in[0];
  const float* cell      = (const float*)d_in[1];
  const int*   Sij       = (const int*)d_in[2];
  const int*   eidx      = (const int*)d_in[3];
  const int*   species   = (const int*)d_in[4];
  const int*   batch     = (const int*)d_in[5];
  const float* W_emb     = (const float*)d_in[6];
  const float* W_xtp     = (const float*)d_in[7];
  const float* W_up      = (const float*)d_in[8];
  const float* W1        = (const float*)d_in[9];
  const float* b1        = (const float*)d_in[10];
  const float* W2        = (const float*)d_in[11];
  const float* b2        = (const float*)d_in[12];
  const float* W3        = (const float*)d_in[13];
  const float* W_down    = (const float*)d_in[14];
  const float* W_sc      = (const float*)d_in[15];
  const float* Wr1       = (const float*)d_in[16];
  const float* br1       = (const float*)d_in[17];
  const float* Wr2       = (const float*)d_in[18];
  float* out = (float*)d_out;
  (void)in_sizes; (void)n_in; (void)out_size;

  const size_t NEED_BASE  = 120000000;
  const size_t NEED_FUSED = 166500000;
  if (ws_size < NEED_BASE) {
    k_dbg<<<dim3(2), dim3(64), 0, stream>>>(out, (float)(ws_size >> 20));
    return;
  }
  const bool fused = ws_size >= NEED_FUSED;

  char* ws = (char*)d_ws;
  size_t off = 0;
  auto alloc = [&](size_t bytes) -> void* {
    void* p = ws + off;
    off += (bytes + 255) & ~(size_t)255;
    return p;
  };
  __half*    Yb      = (__half*)alloc((size_t)EE*16*2);  // 12.8 MB
  __half*    efb     = (__half*)alloc((size_t)EE*8*2);   //  6.4 MB
  float*     hb      = (float*)alloc((size_t)NN*512*4);  // 20.5 MB
  __half*    huA     = (__half*)alloc((size_t)NN*512*2); // 10.2 MB
  __half*    huB     = (__half*)alloc((size_t)NN*512*2); // 10.2 MB
  float*     xnodeb  = (float*)alloc((size_t)NN*4);
  float*     node_eb = (float*)alloc((size_t)NN*4);
  int*       offb    = (int*)alloc((size_t)(NN+1)*4);
  int*       curb    = (int*)alloc((size_t)NN*4);
  int2*      elistb  = (int2*)alloc((size_t)EE*8);       //  3.2 MB
  _Float16*  W2tb    = (_Float16*)alloc((size_t)NLAYER*64*64*2);
  _Float16*  W3tb    = (_Float16*)alloc((size_t)NLAYER*64*256*2);
  float*     hu0b    = (float*)alloc((size_t)SS*CC*4);   // 512 B
  __half*    hm2A    = (__half*)alloc((size_t)EE*64*2);  // 51.2 MB
  __half*    hm2B    = fused ? (__half*)alloc((size_t)EE*64*2) : hm2A;

  dim3 blk(256);
  dim3 blk512(512);
  hipMemsetAsync(curb, 0, (size_t)NN*4, stream);
  k_pre<<<dim3(4568), blk, 0, stream>>>(positions, cell, Sij, eidx, batch,
      Yb, efb, species, W_emb, W_xtp, hb, xnodeb, node_eb,
      W2, W3, W2tb, W3tb, W_up, hu0b, curb);
  k_csr_scan<<<dim3(GG), dim3(128), 0, stream>>>(curb, offb, curb);
  // fill edges + layer-0 hu fill + layer-0 mlp in one launch
  k_csr_fill<<<dim3(2813 + MLPB), blk, 0, stream>>>(eidx, curb, elistb,
      hu0b, species, huA,
      efb, W1 + 0, b1 + 0, W2tb + 0, b2 + 0, hm2A);

  __half* hin = huA; __half* hout = huB;
  __half* hm2_cur = hm2A; __half* hm2_nxt = hm2B;
  for (int layer = 0; layer < NLAYER; ++layer) {
    int has_next = (layer + 1 < NLAYER) ? 1 : 0;
    int do_mlp = (fused && has_next) ? 1 : 0;
    int nl = has_next ? layer + 1 : 0;
    k_gather<<<dim3(NN/2 + (do_mlp ? MLPB2 : 0)), blk512, 0, stream>>>(
        elistb, offb, Yb, hm2_cur,
        W3tb + layer*16384, hin,
        species, xnodeb,
        W_down + layer*4096, W_sc + layer*16384,
        Wr1 + layer*CC*64, br1 + layer*64, Wr2 + layer*64, node_eb,
        W_up + (has_next ? (layer+1)*4096 : 0), hout, hb, has_next,
        do_mlp, efb,
        W1 + nl*NBES*64, b1 + nl*64, W2tb + nl*4096, b2 + nl*64,
        hm2_nxt);
    if (!fused && has_next) {
      k_mlp<<<dim3(MLPB), blk, 0, stream>>>(efb,
          W1 + (layer+1)*NBES*64, b1 + (layer+1)*64,
          W2tb + (layer+1)*4096, b2 + (layer+1)*64, hm2A);
    }
    __half* tmp = hin; hin = hout; hout = tmp;
    if (fused) { __half* t2 = hm2_cur; hm2_cur = hm2_nxt; hm2_nxt = t2; }
  }
  k_out<<<dim3(GG), dim3(128), 0, stream>>>(node_eb, out);
}

// Round 16
// 818.860 us; speedup vs baseline: 1.0627x; 1.0627x over previous
//
#include <hip/hip_runtime.h>
#include <hip/hip_bf16.h>
#include <hip/hip_fp16.h>
#include <stdint.h>

// Problem constants (match reference)
#define NN   10000
#define GG   100
#define NPG  100
#define EE   400000
#define EPG  4000
#define CC   32
#define LM   16
#define SS   4
#define NBES 8
#define NLAYER 3
#define INV_AVG (1.0f/40.0f)
#define MLPB 6256   // mlp block count (8*782 >= EE/64)

typedef _Float16 f16x8 __attribute__((ext_vector_type(8)));
typedef _Float16 f16x4 __attribute__((ext_vector_type(4)));
typedef _Float16 f16x2 __attribute__((ext_vector_type(2)));
typedef float    f32x4 __attribute__((ext_vector_type(4)));

__device__ __forceinline__ float siluf(float x) { return x / (1.0f + __expf(-x)); }
__device__ __forceinline__ int lof(int m) { return (m >= 1) + (m >= 4) + (m >= 9); }
__device__ __forceinline__ f16x2 asf16x2(unsigned u) {
  union { unsigned u; f16x2 f; } x; x.u = u; return x.f;
}

// async global->LDS, 16B per lane; LDS dst = uniform base + lane*16
__device__ __forceinline__ void gload_lds16(const void* g, void* l) {
  __builtin_amdgcn_global_load_lds(
      (const __attribute__((address_space(1))) unsigned int*)g,
      (__attribute__((address_space(3))) unsigned int*)l, 16, 0, 0);
}

// ---------------------------------------------------------------------------
// geometry body (per edge): Y[E,16] f16, ef[E,8] f16
// ---------------------------------------------------------------------------
__device__ __forceinline__ void geom_body(
    int e, const float* __restrict__ pos, const float* __restrict__ cell,
    const int* __restrict__ Sij, const int* __restrict__ eidx,
    const int* __restrict__ batch, __half* __restrict__ Y, __half* __restrict__ ef)
{
  int ia = eidx[e], ja = eidx[EE + e];
  int g = batch[ia];
  float s0 = (float)Sij[e*3+0], s1 = (float)Sij[e*3+1], s2 = (float)Sij[e*3+2];
  const float* cg = cell + g*9;
  float shx = s0*cg[0] + s1*cg[3] + s2*cg[6];
  float shy = s0*cg[1] + s1*cg[4] + s2*cg[7];
  float shz = s0*cg[2] + s1*cg[5] + s2*cg[8];
  float rx = (pos[ja*3+0] - pos[ia*3+0] + shx) / 6.0f;
  float ry = (pos[ja*3+1] - pos[ia*3+1] + shy) / 6.0f;
  float rz = (pos[ja*3+2] - pos[ia*3+2] + shz) / 6.0f;
  float r2 = rx*rx + ry*ry + rz*rz;
  float r  = sqrtf(r2);
  float rs = (r > 1e-9f) ? r : 1e-9f;
  float inv = 1.0f / rs;
  float x = rx*inv, y = ry*inv, z = rz*inv;

  const float s3   = 1.7320508075688772f;
  const float s15  = 3.872983346207417f;
  const float s5h  = 1.118033988749895f;
  const float s15h = 1.9364916731037085f;
  const float s358 = 2.091650066335189f;
  const float s105 = 10.246950765959598f;
  const float s218 = 1.620185174601965f;
  const float s7h  = 1.3228756555322954f;
  const float s105h= 5.123475382979799f;

  float xx = x*x, yy = y*y, zz = z*z;
  float yv[16];
  yv[0]  = 1.0f;
  yv[1]  = s3*x;  yv[2] = s3*y;  yv[3] = s3*z;
  yv[4]  = s15*x*y; yv[5] = s15*y*z; yv[6] = s5h*(3.0f*zz - 1.0f);
  yv[7]  = s15*x*z; yv[8] = s15h*(xx - yy);
  yv[9]  = s358*y*(3.0f*xx - yy);
  yv[10] = s105*x*y*z;
  yv[11] = s218*y*(5.0f*zz - 1.0f);
  yv[12] = s7h*(5.0f*zz*z - 3.0f*z);
  yv[13] = s218*x*(5.0f*zz - 1.0f);
  yv[14] = s105h*z*(xx - yy);
  yv[15] = s358*x*(xx - 3.0f*yy);

  union { __half h[16]; uint4 u[2]; } yp;
  #pragma unroll
  for (int i = 0; i < 16; ++i) yp.h[i] = __float2half(yv[i]);
  uint4* Yp = (uint4*)(Y + (size_t)e*16);
  Yp[0] = yp.u[0];
  Yp[1] = yp.u[1];

  float f = 0.0f;
  if (r < 1.0f) f = 1.0f - 6.0f*r2 + 8.0f*r2*r - 3.0f*r2*r2;
  float c1 = 1.4142135623730951f * f * inv;
  float ang = 3.14159265358979323846f * rs;
  float sn = __sinf(ang), cn = __cosf(ang);
  float twoc = 2.0f * cn;
  float sprev = 0.0f, scur = sn;
  union { __half h[8]; uint4 u; } p;
  #pragma unroll
  for (int n1 = 1; n1 <= NBES; ++n1) {
    p.h[n1-1] = __float2half(c1 * scur);
    float snext = twoc * scur - sprev;
    sprev = scur; scur = snext;
  }
  *(uint4*)(ef + (size_t)e*8) = p.u;
}

// ---------------------------------------------------------------------------
// k_pre: geom (1563) | init (1250) | wconv+hu0 (192) | csr_count (1563)
// ---------------------------------------------------------------------------
__global__ __launch_bounds__(256) void k_pre(
    const float* __restrict__ pos, const float* __restrict__ cell,
    const int* __restrict__ Sij, const int* __restrict__ eidx,
    const int* __restrict__ batch, __half* __restrict__ Y, __half* __restrict__ ef,
    const int* __restrict__ species, const float* __restrict__ W_emb,
    const float* __restrict__ W_xtp, float* __restrict__ h,
    float* __restrict__ xnode, float* __restrict__ node_e,
    const float* __restrict__ W2, const float* __restrict__ W3,
    _Float16* __restrict__ W2t, _Float16* __restrict__ W3t,
    const float* __restrict__ W_up0, float* __restrict__ hu0,
    int* __restrict__ cnt)
{
  int b = blockIdx.x, t = threadIdx.x;
  if (b < 1563) {
    int e = b*256 + t;
    if (e < EE) geom_body(e, pos, cell, Sij, eidx, batch, Y, ef);
  } else if (b < 2813) {
    int idx = (b - 1563)*256 + t;
    if (idx < NN*CC) {
      int n = idx / CC, c = idx % CC;
      int sp = species[n];
      float h0 = W_emb[sp*CC + c];
      float* hp = h + (size_t)n*512 + c*16;
      hp[0] = h0;
      #pragma unroll
      for (int m = 1; m < 16; ++m) hp[m] = 0.0f;
      if (c == 0) {
        float xn = 0.0f;
        for (int c2 = 0; c2 < CC; ++c2) xn += W_emb[sp*CC + c2] * W_xtp[c2*SS + sp];
        xnode[n] = xn;
        node_e[n] = 0.0f;
      }
    }
  } else if (b < 3005) {
    int idx = (b - 2813)*256 + t;
    if (idx < NLAYER*64*64) {
      int l = idx / 4096, rem = idx % 4096, k = rem / 64, j = rem % 64;
      W2t[l*4096 + j*64 + k] = (_Float16)W2[idx];
    }
    if (idx < NLAYER*64*256) {
      int l = idx / 16384, rem = idx % 16384, k = rem / 256, j = rem % 256;
      W3t[l*16384 + j*64 + k] = (_Float16)W3[idx];
    }
    // layer-0 hu table: hu0[sp][d] = sum_c W_emb[sp,c] * W_up[0,0,c,d]
    // (h is zero except m=0 at layer 0, and h[:,:,0] = W_emb[species])
    // two 16-c partials then add -> mirrors original ch-split + shfl_xor order
    if (b == 2813 && idx < SS*CC) {
      int sp = idx >> 5, dd = idx & 31;
      float p0 = 0.0f, p1 = 0.0f;
      for (int c2 = 0; c2 < 16; ++c2)  p0 += W_emb[sp*CC + c2] * W_up0[c2*32 + dd];
      for (int c2 = 16; c2 < 32; ++c2) p1 += W_emb[sp*CC + c2] * W_up0[c2*32 + dd];
      hu0[idx] = p0 + p1;
    }
  } else {
    int e = (b - 3005)*256 + t;
    if (e < EE) atomicAdd(&cnt[eidx[e]], 1);
  }
}

// ---------------------------------------------------------------------------
// CSR scan
// ---------------------------------------------------------------------------
__global__ __launch_bounds__(128) void k_csr_scan(
    const int* __restrict__ cnt, int* __restrict__ off, int* __restrict__ cursor) {
  __shared__ int s[128];
  int g = blockIdx.x, t = threadIdx.x;
  int own = (t < NPG) ? cnt[g*NPG + t] : 0;
  s[t] = own;
  __syncthreads();
  #pragma unroll
  for (int d = 1; d < 128; d <<= 1) {
    int v = (t >= d) ? s[t-d] : 0;
    __syncthreads();
    s[t] += v;
    __syncthreads();
  }
  if (t < NPG) {
    int o = g*EPG + s[t] - own;
    off[g*NPG + t] = o;
    cursor[g*NPG + t] = o;
    if (g == GG-1 && t == NPG-1) off[NN] = EE;
  }
}

// ---------------------------------------------------------------------------
// mlp body (per block of 64 edges): ef(8)->hm1(64) VALU -> hm2(64) MFMA f16
// ---------------------------------------------------------------------------
__device__ __forceinline__ void mlp_body(
    int mb, int t, _Float16* pool16,
    const __half* __restrict__ ef, const float* __restrict__ W1,
    const float* __restrict__ b1, const _Float16* __restrict__ W2t,
    const float* __restrict__ b2, __half* __restrict__ hm2)
{
  int eb = (mb & 7) * 782 + (mb >> 3);
  if (eb >= EE/64) return;
  int wv = t >> 6, lane = t & 63;
  int ln15 = lane & 15, quad = lane >> 4;
  _Float16* hm1 = pool16 + wv*(16*72);
  size_t e16 = (size_t)eb*64 + wv*16;

  union { uint4 u; __half hh[8]; } efv;
  efv.u = *(const uint4*)(ef + (e16 + ln15)*8);
  float ev[8];
  #pragma unroll
  for (int k = 0; k < 8; ++k) ev[k] = __half2float(efv.hh[k]);
  #pragma unroll
  for (int p = 0; p < 4; ++p) {
    int j0 = p*16 + quad*4;
    float4 a = *(const float4*)(b1 + j0);
    #pragma unroll
    for (int k = 0; k < 8; ++k) {
      const float4 w = *(const float4*)(W1 + k*64 + j0);
      a.x += ev[k]*w.x; a.y += ev[k]*w.y; a.z += ev[k]*w.z; a.w += ev[k]*w.w;
    }
    f16x4 pk;
    pk[0] = (_Float16)siluf(a.x);
    pk[1] = (_Float16)siluf(a.y);
    pk[2] = (_Float16)siluf(a.z);
    pk[3] = (_Float16)siluf(a.w);
    *(f16x4*)&hm1[ln15*72 + j0] = pk;
  }

  f16x8 a0 = *(const f16x8*)(hm1 + ln15*72 + quad*8);
  f16x8 a1 = *(const f16x8*)(hm1 + ln15*72 + 32 + quad*8);
  #pragma unroll
  for (int cg = 0; cg < 4; ++cg) {
    int col = cg*16 + ln15;
    f32x4 d = {0.f, 0.f, 0.f, 0.f};
    d = __builtin_amdgcn_mfma_f32_16x16x32_f16(a0, *(const f16x8*)(W2t + (size_t)col*64 + quad*8), d, 0, 0, 0);
    d = __builtin_amdgcn_mfma_f32_16x16x32_f16(a1, *(const f16x8*)(W2t + (size_t)col*64 + 32 + quad*8), d, 0, 0, 0);
    float bb = b2[col];
    #pragma unroll
    for (int r = 0; r < 4; ++r)
      hm2[(e16 + quad*4 + r)*64 + col] = __float2half(siluf(d[r] + bb));
  }
}

// standalone mlp (used by the non-fused fallback path)
__global__ __launch_bounds__(256) void k_mlp(
    const __half* __restrict__ ef, const float* __restrict__ W1,
    const float* __restrict__ b1, const _Float16* __restrict__ W2t,
    const float* __restrict__ b2, __half* __restrict__ hm2)
{
  __shared__ _Float16 pool16[4*16*72];
  mlp_body(blockIdx.x, threadIdx.x, pool16, ef, W1, b1, W2t, b2, hm2);
}

// ---------------------------------------------------------------------------
// k_csr_fill: edges fill (1563) | layer-0 hu fill (1250) | layer-0 mlp (MLPB)
// The three parts are data-independent; fusing them lets the short fill
// blocks overlap with the mlp compute (one less serialized launch).
// ---------------------------------------------------------------------------
__global__ __launch_bounds__(256) void k_csr_fill(
    const int* __restrict__ eidx, int* __restrict__ cursor, int2* __restrict__ elist,
    const float* __restrict__ hu0, const int* __restrict__ species,
    __half* __restrict__ huA,
    const __half* __restrict__ ef, const float* __restrict__ W1,
    const float* __restrict__ b1, const _Float16* __restrict__ W2t,
    const float* __restrict__ b2, __half* __restrict__ hm2) {
  __shared__ _Float16 pool16[4*16*72];
  int b = blockIdx.x;
  if (b < 1563) {
    int e = b * 256 + threadIdx.x;
    if (e >= EE) return;
    int ia = eidx[e], ja = eidx[EE + e];
    int pos = atomicAdd(&cursor[ia], 1);
    elist[pos] = make_int2(e*128, ja*1024);
    return;
  }
  if (b < 2813) {
    int idx = (b - 1563)*256 + threadIdx.x;   // [0, NN*32)
    if (idx >= NN*CC) return;
    int n = idx >> 5, d = idx & 31;
    __half h0 = __float2half(hu0[species[n]*CC + d]);
    union { __half hh[2]; unsigned u; } w; w.hh[0] = h0; w.hh[1] = __half(0.0f);
    uint4 v0 = make_uint4(w.u, 0u, 0u, 0u);
    uint4 v1 = make_uint4(0u, 0u, 0u, 0u);
    uint4* p = (uint4*)(huA + (size_t)n*512 + d*16);
    p[0] = v0;
    p[1] = v1;
    return;
  }
  mlp_body(b - 2813, threadIdx.x, pool16, ef, W1, b1, W2t, b2, hm2);
}

// ---------------------------------------------------------------------------
// k_gather: optional fused next-layer mlp blocks first (do_mlp), then
// block-per-node gather.  (R12 binary: TILE=16, post-barrier prefetch,
// verified 260us/dispatch.)
// Layout (bytes): rww 0..8704 | hu_s 8704..25600 | Ys 25600..26624
// ---------------------------------------------------------------------------
__global__ __launch_bounds__(256) void k_gather(
    const int2* __restrict__ elist, const int* __restrict__ off,
    const __half* __restrict__ Y, const __half* __restrict__ hm2,
    const _Float16* __restrict__ W3t, const __half* __restrict__ hu_in,
    const int* __restrict__ species, const float* __restrict__ xnode,
    const float* __restrict__ Wd, const float* __restrict__ Wsc,
    const float* __restrict__ Wr1, const float* __restrict__ br1,
    const float* __restrict__ Wr2, float* __restrict__ node_e,
    const float* __restrict__ Wu_next, __half* __restrict__ hu_out,
    float* __restrict__ h, int has_next,
    int do_mlp, const __half* __restrict__ ef,
    const float* __restrict__ W1n, const float* __restrict__ b1n,
    const _Float16* __restrict__ W2tn, const float* __restrict__ b2n,
    __half* __restrict__ hm2_next)
{
  __shared__ float pool[6656];   // 26624 B

  int b = blockIdx.x, t = threadIdx.x;
  if (do_mlp) {
    if (b < MLPB) {
      mlp_body(b, t, (_Float16*)pool, ef, W1n, b1n, W2tn, b2n, hm2_next);
      return;
    }
    b -= MLPB;
  }
  _Float16* rw_base = (_Float16*)pool;
  char* hu_sc = (char*)pool + 8704;
  char* Ys_c  = (char*)pool + 25600;
  float* al_s = pool;
  float* h2_s = pool + 512;

  int n = (b & 7) * (NN/8) + (b >> 3);   // XCD-locality swizzle
  int beg = off[n], deg = off[n+1] - beg;

  int lane = t & 63, wv = t >> 6;
  int ln15 = lane & 15, quad = lane >> 4;
  _Float16* rww = rw_base + wv*(16*68);
  const char* rwc = (const char*)rww;
  const char* hm2c = (const char*)hm2;
  const char* Yc   = (const char*)Y;
  const char* huc  = (const char*)hu_in;

  float hreg0 = h[(size_t)n*512 + t];
  float hreg1 = h[(size_t)n*512 + t + 256];

  // edge-loop lane mapping: lane = half*32 + cl*4 + mq
  int mq   = lane & 3;          // m-quad: m = mq*4 .. mq*4+3
  int cl   = (lane >> 2) & 7;   // channel within wave
  int half = lane >> 5;         // edge parity
  int c    = wv*8 + cl;
  int m0q  = mq*4;
  int la0 = lof(m0q),   lb0 = lof(m0q+1);
  int la1 = lof(m0q+2), lb1 = lof(m0q+3);
  unsigned sel0 = (unsigned)(2*la0) | ((unsigned)(2*la0+1)<<8)
                | ((unsigned)(2*lb0)<<16) | ((unsigned)(2*lb0+1)<<24);
  unsigned sel1 = (unsigned)(2*la1) | ((unsigned)(2*la1+1)<<8)
                | ((unsigned)(2*lb1)<<16) | ((unsigned)(2*lb1+1)<<24);
  unsigned huconst = (unsigned)(c*32 + mq*8);

  // persistent W3 fragments: this wave's 64 output columns
  f16x8 w3A[4], w3B[4];
  #pragma unroll
  for (int cg = 0; cg < 4; ++cg) {
    int colg = (cg < 2) ? (wv*32 + cg*16 + ln15)
                        : (128 + wv*32 + (cg-2)*16 + ln15);
    w3A[cg] = *(const f16x8*)(W3t + (size_t)colg*64 + quad*8);
    w3B[cg] = *(const f16x8*)(W3t + (size_t)colg*64 + 32 + quad*8);
  }

  float acc0 = 0.f, acc1 = 0.f, acc2 = 0.f, acc3 = 0.f;

  int2 el_cur = make_int2(0, 0);
  f16x8 aA0 = {}, aA1 = {};
  if (deg > 0) {
    int idx = lane < deg ? lane : deg - 1;
    el_cur = elist[beg + idx];
    int eA = __shfl(el_cur.x, ln15);
    aA0 = *(const f16x8*)(hm2c + (unsigned)eA + quad*16);
    aA1 = *(const f16x8*)(hm2c + (unsigned)eA + 64 + quad*16);
  }

  // compute body for edge slot s (all operands in LDS)
  auto edge_compute = [&](int s, f16x2& av0, f16x2& av1) {
    uint2 hj = *(const uint2*)(hu_sc + (unsigned)s*1056 + huconst);   // ds_read_b64
    unsigned hj0b = (unsigned)__builtin_amdgcn_mov_dpp((int)hj.x, 0, 0xf, 0xf, true);
    unsigned hj0s = __builtin_amdgcn_perm(hj0b, hj0b, 0x01000100u);   // splat m=0
    uint2 Ymv = *(const uint2*)(Ys_c + (unsigned)s*32 + mq*8);        // ds_read_b64
    uint2 w0q = *(const uint2*)(rwc + (unsigned)s*136 + cl*8);        // ds_read_b64
    uint2 w1q = *(const uint2*)(rwc + (unsigned)s*136 + cl*8 + 64);   // ds_read_b64
    unsigned w00 = __builtin_amdgcn_perm(w0q.y, w0q.x, sel0);
    unsigned w01 = __builtin_amdgcn_perm(w0q.y, w0q.x, sel1);
    unsigned w10 = __builtin_amdgcn_perm(w1q.y, w1q.x, sel0);
    unsigned w11 = __builtin_amdgcn_perm(w1q.y, w1q.x, sel1);
    f16x2 hj0v = asf16x2(hj0s);
    av0 += asf16x2(w00) * (asf16x2(Ymv.x) * hj0v) + asf16x2(w10) * asf16x2(hj.x);
    av1 += asf16x2(w01) * (asf16x2(Ymv.y) * hj0v) + asf16x2(w11) * asf16x2(hj.y);
  };

  for (int base = 0; base < deg; base += 16) {
    int cnt = deg - base; if (cnt > 16) cnt = 16;

    if (base > 0) __syncthreads();   // A: prior compute done; prefetch tail drained

    // STAGE: hu rows (4 per wave, 1KB each, async) + Y rows (wave 0)
    #pragma unroll
    for (int q = 0; q < 4; ++q) {
      int s = wv*4 + q;
      if (s < cnt) {
        int rowoff = __shfl(el_cur.y, s);
        gload_lds16(huc + (unsigned)rowoff + lane*16, hu_sc + s*1056);
      }
    }
    if (wv == 0) {
      int yoff = __shfl(el_cur.x, lane >> 1) >> 2;   // e*32 byte offset
      gload_lds16(Yc + (unsigned)yoff + (lane & 1)*16, Ys_c);
    }

    // MFMA phase (reg-resident W3; no VMEM) + packed ds_write
    __builtin_amdgcn_s_setprio(1);
    #pragma unroll
    for (int cg = 0; cg < 4; ++cg) {
      f32x4 dA = {0.f, 0.f, 0.f, 0.f};
      dA = __builtin_amdgcn_mfma_f32_16x16x32_f16(w3A[cg], aA0, dA, 0, 0, 0);
      dA = __builtin_amdgcn_mfma_f32_16x16x32_f16(w3B[cg], aA1, dA, 0, 0, 0);
      f16x4 pA;
      #pragma unroll
      for (int r = 0; r < 4; ++r) pA[r] = (_Float16)dA[r];
      *(f16x4*)&rww[ln15*68 + cg*16 + quad*4] = pA;      // ds_write_b64
    }
    __builtin_amdgcn_s_setprio(0);

    __syncthreads();   // B: staged hu/Y + rww visible (drains stage only)

    // PREFETCH k+1 (issued now; chain lands under the compute phase)
    int2 el_nxt = el_cur;
    f16x8 nA0 = aA0, nA1 = aA1;
    if (base + 16 < deg) {
      int idx = base + 16 + lane;
      if (idx >= deg) idx = deg - 1;
      el_nxt = elist[beg + idx];
      int eA = __shfl(el_nxt.x, ln15);
      nA0 = *(const f16x8*)(hm2c + (unsigned)eA + quad*16);
      nA1 = *(const f16x8*)(hm2c + (unsigned)eA + 64 + quad*16);
    }

    // COMPUTE: pure VALU + LDS, halves split the edges
    f16x2 av0 = {(_Float16)0.f, (_Float16)0.f};
    f16x2 av1 = {(_Float16)0.f, (_Float16)0.f};
    int nfull = cnt >> 1;
    #pragma unroll 8
    for (int i = 0; i < nfull; ++i) edge_compute(2*i + half, av0, av1);
    if ((cnt & 1) && half == 0) edge_compute(cnt - 1, av0, av1);
    acc0 += (float)av0[0]; acc1 += (float)av0[1];
    acc2 += (float)av1[0]; acc3 += (float)av1[1];

    el_cur = el_nxt;
    aA0 = nA0; aA1 = nA1;
  }

  // combine the two edge-halves
  acc0 += __shfl_xor(acc0, 32);
  acc1 += __shfl_xor(acc1, 32);
  acc2 += __shfl_xor(acc2, 32);
  acc3 += __shfl_xor(acc3, 32);

  __syncthreads();   // tile phase done -> overlay safe

  if (half == 0) {
    *(float4*)&al_s[c*16 + m0q] =
        make_float4(acc0*INV_AVG, acc1*INV_AVG, acc2*INV_AVG, acc3*INV_AVG);
  }
  h2_s[t]       = hreg0;
  h2_s[t + 256] = hreg1;
  __syncthreads();

  int sp = species[n];
  float xn = xnode[n];
  int d = lane & 31, ch = lane >> 5;
  #pragma unroll
  for (int mi = 0; mi < 4; ++mi) {
    int m = wv*4 + mi;
    int l = lof(m);
    const float* wd  = Wd  + l*1024 + d;
    const float* wsc = Wsc + l*4096 + sp*32 + d;
    float a = 0.0f, s = 0.0f;
    #pragma unroll 4
    for (int cc = 0; cc < 16; ++cc) {
      int c2 = cc + ch*16;
      a += al_s[c2*16 + m] * wd[c2*32];
      s += h2_s[c2*16 + m] * wsc[c2*128];
    }
    a += __shfl_xor(a, 32);
    s += __shfl_xor(s, 32);
    float hn = a*xn + s;
    if (ch == 0) h2_s[d*16 + m] = hn;       // out overlay (wave-excl col)
    if (has_next) {
      const float* wu = Wu_next + l*1024 + d;
      float u = 0.0f;
      #pragma unroll 4
      for (int cc = 0; cc < 16; ++cc) {
        int c2 = cc + ch*16;
        u += h2_s[c2*16 + m] * wu[c2*32];    // reads out (same wave wrote)
      }
      u += __shfl_xor(u, 32);
      if (ch == 0) al_s[d*16 + m] = u;      // hu overlay (wave-excl col)
    }
  }

  if (t < 64) {
    float pre = br1[t];
    #pragma unroll 4
    for (int cc = 0; cc < CC; ++cc) pre += h2_s[cc*16] * Wr1[cc*64 + t];
    float v = siluf(pre) * Wr2[t];
    #pragma unroll
    for (int off2 = 32; off2 > 0; off2 >>= 1) v += __shfl_down(v, off2);
    if (t == 0) node_e[n] += siluf(v);
  }
  __syncthreads();   // out/hu complete

  h[(size_t)n*512 + t]       = h2_s[t];
  h[(size_t)n*512 + t + 256] = h2_s[t + 256];
  if (has_next) {
    __half2 o;
    o.x = __float2half(al_s[2*t]);
    o.y = __float2half(al_s[2*t + 1]);
    *(__half2*)(hu_out + (size_t)n*512 + 2*t) = o;
  }
}

// ---------------------------------------------------------------------------
// Kernel: per-graph sum of node energies
// ---------------------------------------------------------------------------
__global__ __launch_bounds__(128) void k_out(
    const float* __restrict__ node_e, float* __restrict__ out)
{
  int g = blockIdx.x, t = threadIdx.x;
  float v = (t < NPG) ? node_e[g*NPG + t] : 0.0f;
  #pragma unroll
  for (int off2 = 32; off2 > 0; off2 >>= 1) v += __shfl_down(v, off2);
  __shared__ float r2[2];
  if ((t & 63) == 0) r2[t >> 6] = v;
  __syncthreads();
  if (t == 0) out[g] = r2[0] + r2[1];
}

// Diagnostic: if workspace too small, report its size (MB) via absmax
__global__ void k_dbg(float* __restrict__ out, float v) {
  int i = blockIdx.x * 64 + threadIdx.x;
  if (i < GG) out[i] = v;
}

// ---------------------------------------------------------------------------
extern "C" void kernel_launch(void* const* d_in, const int* in_sizes, int n_in,
                              void* d_out, int out_size, void* d_ws, size_t ws_size,
                              hipStream_t stream)
{
  const float* positions = (const float*)d_in[0];
  const float* cell      = (const float*)d_in[1];
  const int*   Sij       = (const int*)d_in[2];
  const int*   eidx      = (const int*)d_in[3];
  const int*   species   = (const int*)d_in[4];
  const int*   batch     = (const int*)d_in[5];
  const float* W_emb     = (const float*)d_in[6];
  const float* W_xtp     = (const float*)d_in[7];
  const float* W_up      = (const float*)d_in[8];
  const float* W1        = (const float*)d_in[9];
  const float* b1        = (const float*)d_in[10];
  const float* W2        = (const float*)d_in[11];
  const float* b2        = (const float*)d_in[12];
  const float* W3        = (const float*)d_in[13];
  const float* W_down    = (const float*)d_in[14];
  const float* W_sc      = (const float*)d_in[15];
  const float* Wr1       = (const float*)d_in[16];
  const float* br1       = (const float*)d_in[17];
  const float* Wr2       = (const float*)d_in[18];
  float* out = (float*)d_out;
  (void)in_sizes; (void)n_in; (void)out_size;

  const size_t NEED_BASE  = 120000000;
  const size_t NEED_FUSED = 166500000;
  if (ws_size < NEED_BASE) {
    k_dbg<<<dim3(2), dim3(64), 0, stream>>>(out, (float)(ws_size >> 20));
    return;
  }
  const bool fused = ws_size >= NEED_FUSED;

  char* ws = (char*)d_ws;
  size_t off = 0;
  auto alloc = [&](size_t bytes) -> void* {
    void* p = ws + off;
    off += (bytes + 255) & ~(size_t)255;
    return p;
  };
  __half*    Yb      = (__half*)alloc((size_t)EE*16*2);  // 12.8 MB
  __half*    efb     = (__half*)alloc((size_t)EE*8*2);   //  6.4 MB
  float*     hb      = (float*)alloc((size_t)NN*512*4);  // 20.5 MB
  __half*    huA     = (__half*)alloc((size_t)NN*512*2); // 10.2 MB
  __half*    huB     = (__half*)alloc((size_t)NN*512*2); // 10.2 MB
  float*     xnodeb  = (float*)alloc((size_t)NN*4);
  float*     node_eb = (float*)alloc((size_t)NN*4);
  int*       offb    = (int*)alloc((size_t)(NN+1)*4);
  int*       curb    = (int*)alloc((size_t)NN*4);
  int2*      elistb  = (int2*)alloc((size_t)EE*8);       //  3.2 MB
  _Float16*  W2tb    = (_Float16*)alloc((size_t)NLAYER*64*64*2);
  _Float16*  W3tb    = (_Float16*)alloc((size_t)NLAYER*64*256*2);
  float*     hu0b    = (float*)alloc((size_t)SS*CC*4);   // 512 B
  __half*    hm2A    = (__half*)alloc((size_t)EE*64*2);  // 51.2 MB
  __half*    hm2B    = fused ? (__half*)alloc((size_t)EE*64*2) : hm2A;

  dim3 blk(256);
  hipMemsetAsync(curb, 0, (size_t)NN*4, stream);
  k_pre<<<dim3(4568), blk, 0, stream>>>(positions, cell, Sij, eidx, batch,
      Yb, efb, species, W_emb, W_xtp, hb, xnodeb, node_eb,
      W2, W3, W2tb, W3tb, W_up, hu0b, curb);
  k_csr_scan<<<dim3(GG), dim3(128), 0, stream>>>(curb, offb, curb);
  // fill edges + layer-0 hu fill + layer-0 mlp in one launch
  k_csr_fill<<<dim3(2813 + MLPB), blk, 0, stream>>>(eidx, curb, elistb,
      hu0b, species, huA,
      efb, W1 + 0, b1 + 0, W2tb + 0, b2 + 0, hm2A);

  __half* hin = huA; __half* hout = huB;
  __half* hm2_cur = hm2A; __half* hm2_nxt = hm2B;
  for (int layer = 0; layer < NLAYER; ++layer) {
    int has_next = (layer + 1 < NLAYER) ? 1 : 0;
    int do_mlp = (fused && has_next) ? 1 : 0;
    int nl = has_next ? layer + 1 : 0;
    k_gather<<<dim3(NN + (do_mlp ? MLPB : 0)), blk, 0, stream>>>(
        elistb, offb, Yb, hm2_cur,
        W3tb + layer*16384, hin,
        species, xnodeb,
        W_down + layer*4096, W_sc + layer*16384,
        Wr1 + layer*CC*64, br1 + layer*64, Wr2 + layer*64, node_eb,
        W_up + (has_next ? (layer+1)*4096 : 0), hout, hb, has_next,
        do_mlp, efb,
        W1 + nl*NBES*64, b1 + nl*64, W2tb + nl*4096, b2 + nl*64,
        hm2_nxt);
    if (!fused && has_next) {
      k_mlp<<<dim3(MLPB), blk, 0, stream>>>(efb,
          W1 + (layer+1)*NBES*64, b1 + (layer+1)*64,
          W2tb + (layer+1)*4096, b2 + (layer+1)*64, hm2A);
    }
    __half* tmp = hin; hin = hout; hout = tmp;
    if (fused) { __half* t2 = hm2_cur; hm2_cur = hm2_nxt; hm2_nxt = t2; }
  }
  k_out<<<dim3(GG), dim3(128), 0, stream>>>(node_eb, out);
}